// Round 1
// baseline (1567.869 us; speedup 1.0000x reference)
//
#include <hip/hip_runtime.h>
#include <hip/hip_fp16.h>
#include <stdint.h>
#include <stddef.h>

typedef _Float16 f16x8 __attribute__((ext_vector_type(8)));
typedef float    f32x4 __attribute__((ext_vector_type(4)));

#define B_ 4
#define N_ 2048
#define C_ 1024
#define H_ 16
#define D_ 64
#define M_ 8192  /* B_*N_ */

// ws layout (f16 element offsets): 4 weights (4x1M), Q,K,V,O (4x8M) = 36M elems = 72MB
#define OFF_W ((size_t)0)
#define OFF_Q ((size_t)4<<20)
#define OFF_K ((size_t)12<<20)
#define OFF_V ((size_t)20<<20)
#define OFF_O ((size_t)28<<20)

__global__ __launch_bounds__(256) void cvt_w(const float* __restrict__ s,
                                             _Float16* __restrict__ d, int n4) {
    int i = blockIdx.x * 256 + threadIdx.x;
    if (i < n4) {
        float4 v = *(((const float4*)s) + i);
        union { _Float16 h[4]; uint2 u; } pk;
        pk.h[0] = (_Float16)v.x; pk.h[1] = (_Float16)v.y;
        pk.h[2] = (_Float16)v.z; pk.h[3] = (_Float16)v.w;
        *(((uint2*)d) + i) = pk.u;
    }
}

// Y[m][n] = sum_k X[m][k] * W[n][k];  X fp32 (8192x1024), W f16 (1024x1024), Y f16
__global__ __launch_bounds__(256) void qkv_gemm(const float* __restrict__ xq,
                                                const float* __restrict__ xk,
                                                const float* __restrict__ xv,
                                                _Float16* __restrict__ ws) {
    __shared__ _Float16 As[128 * 72];
    __shared__ _Float16 Bs[128 * 72];
    const int z = blockIdx.z;
    const float* __restrict__ X = (z == 0) ? xq : (z == 1) ? xk : xv;
    const _Float16* __restrict__ W = ws + OFF_W + (size_t)z * (1u << 20);
    _Float16* __restrict__ Y = ws + OFF_Q + (size_t)z * (8u << 20);
    const int t = threadIdx.x;
    const int wv = t >> 6, ln = t & 63, lr = ln & 15, lq = ln >> 4;
    const int wr = (wv >> 1) * 64, wc = (wv & 1) * 64;
    const int m0 = blockIdx.y * 128, n0 = blockIdx.x * 128;
    f32x4 acc[4][4] = {};
    for (int kt = 0; kt < 16; ++kt) {
        const int k0 = kt * 64;
        // stage A: 128x64 fp32 -> f16 LDS (2048 float4 chunks, 8/thread)
        #pragma unroll
        for (int i = 0; i < 8; i++) {
            int fi = i * 256 + t;
            int row = fi >> 4, c4 = fi & 15;
            float4 v = *(const float4*)(X + (size_t)(m0 + row) * C_ + k0 + c4 * 4);
            union { _Float16 h[4]; uint2 u; } pk;
            pk.h[0] = (_Float16)v.x; pk.h[1] = (_Float16)v.y;
            pk.h[2] = (_Float16)v.z; pk.h[3] = (_Float16)v.w;
            *(uint2*)&As[row * 72 + c4 * 4] = pk.u;
        }
        // stage B: 128x64 f16 (1024 16B-chunks, 4/thread)
        #pragma unroll
        for (int i = 0; i < 4; i++) {
            int ci = i * 256 + t;
            int row = ci >> 3, c8 = ci & 7;
            f16x8 v = *(const f16x8*)(W + (size_t)(n0 + row) * C_ + k0 + c8 * 8);
            *(f16x8*)&Bs[row * 72 + c8 * 8] = v;
        }
        __syncthreads();
        #pragma unroll
        for (int ks = 0; ks < 2; ++ks) {
            f16x8 af[4], bf[4];
            #pragma unroll
            for (int r = 0; r < 4; r++)
                af[r] = *(const f16x8*)&As[(wr + r * 16 + lr) * 72 + ks * 32 + lq * 8];
            #pragma unroll
            for (int c = 0; c < 4; c++)
                bf[c] = *(const f16x8*)&Bs[(wc + c * 16 + lr) * 72 + ks * 32 + lq * 8];
            #pragma unroll
            for (int r = 0; r < 4; r++)
                #pragma unroll
                for (int c = 0; c < 4; c++)
                    acc[r][c] = __builtin_amdgcn_mfma_f32_16x16x32_f16(af[r], bf[c], acc[r][c], 0, 0, 0);
        }
        __syncthreads();
    }
    // epilogue: C/D layout col=lane&15, row=quad*4+reg
    #pragma unroll
    for (int r = 0; r < 4; r++)
        #pragma unroll
        for (int c = 0; c < 4; c++) {
            int col = n0 + wc + c * 16 + lr;
            #pragma unroll
            for (int g = 0; g < 4; ++g) {
                int row = m0 + wr + r * 16 + lq * 4 + g;
                Y[(size_t)row * C_ + col] = (_Float16)acc[r][c][g];
            }
        }
}

// per (b,h): S = Q K^T * scale -> sigmoid -> attn (fp32 out) ; O += P V (f16 to ws)
__global__ __launch_bounds__(256) void attn_kernel(_Float16* __restrict__ ws,
                                                   float* __restrict__ attn_out) {
    __shared__ _Float16 Ks[64 * 72];
    __shared__ _Float16 VTs[64 * 72];
    __shared__ _Float16 Ps[128 * 72];
    const int t = threadIdx.x;
    const int wv = t >> 6, ln = t & 63, lr = ln & 15, lq = ln >> 4;
    const int bh = blockIdx.y, b = bh >> 4, h = bh & 15;
    const int q0 = blockIdx.x * 128;
    const _Float16* Q = ws + OFF_Q;
    const _Float16* K = ws + OFF_K;
    const _Float16* V = ws + OFF_V;
    _Float16* O = ws + OFF_O;
    float* attnb = attn_out + (size_t)bh * N_ * N_;
    // preload Q A-frags (A[m=lane&15][k=quad*8+j]): wave rows [wv*32, wv*32+32)
    f16x8 qf[2][2];
    #pragma unroll
    for (int r = 0; r < 2; r++)
        #pragma unroll
        for (int ks = 0; ks < 2; ks++) {
            int row = b * N_ + q0 + wv * 32 + r * 16 + lr;
            qf[r][ks] = *(const f16x8*)(Q + (size_t)row * C_ + h * D_ + ks * 32 + lq * 8);
        }
    f32x4 oacc[2][4] = {};
    for (int mt = 0; mt < 32; ++mt) {
        const int m0 = mt * 64;
        __syncthreads();  // guard staging vs prev-iter LDS reads
        // stage K (row-major) and V (transposed) tiles: 64x64 f16 each
        #pragma unroll
        for (int i = 0; i < 2; i++) {
            int ci = i * 256 + t;
            int row = ci >> 3, c8 = ci & 7;
            const size_t gofs = (size_t)(b * N_ + m0 + row) * C_ + h * D_ + c8 * 8;
            f16x8 kv = *(const f16x8*)(K + gofs);
            *(f16x8*)&Ks[row * 72 + c8 * 8] = kv;
            f16x8 vvv = *(const f16x8*)(V + gofs);
            #pragma unroll
            for (int j = 0; j < 8; j++) VTs[(c8 * 8 + j) * 72 + row] = vvv[j];
        }
        __syncthreads();
        // S = Q K^T  (S rows: wave's 32 q-rows; cols: 64 m)
        f32x4 sacc[2][4] = {};
        #pragma unroll
        for (int ks = 0; ks < 2; ks++) {
            f16x8 bk[4];
            #pragma unroll
            for (int c = 0; c < 4; c++)
                bk[c] = *(const f16x8*)&Ks[(c * 16 + lr) * 72 + ks * 32 + lq * 8];
            #pragma unroll
            for (int r = 0; r < 2; r++)
                #pragma unroll
                for (int c = 0; c < 4; c++)
                    sacc[r][c] = __builtin_amdgcn_mfma_f32_16x16x32_f16(qf[r][ks], bk[c], sacc[r][c], 0, 0, 0);
        }
        // sigmoid (fp32), write P to LDS in natural [n][m] layout
        #pragma unroll
        for (int r = 0; r < 2; r++)
            #pragma unroll
            for (int c = 0; c < 4; c++)
                #pragma unroll
                for (int g = 0; g < 4; g++) {
                    float x = sacc[r][c][g] * 0.125f;
                    float p = 1.0f / (1.0f + __expf(-x));
                    Ps[(wv * 32 + r * 16 + lq * 4 + g) * 72 + c * 16 + lr] = (_Float16)p;
                }
        __syncthreads();
        // O += P V : A-frags from Ps, B-frags from VTs (both 16B LDS reads)
        #pragma unroll
        for (int ks = 0; ks < 2; ks++) {
            f16x8 ap[2], bv[4];
            #pragma unroll
            for (int r = 0; r < 2; r++)
                ap[r] = *(const f16x8*)&Ps[(wv * 32 + r * 16 + lr) * 72 + ks * 32 + lq * 8];
            #pragma unroll
            for (int d = 0; d < 4; d++)
                bv[d] = *(const f16x8*)&VTs[(d * 16 + lr) * 72 + ks * 32 + lq * 8];
            #pragma unroll
            for (int r = 0; r < 2; r++)
                #pragma unroll
                for (int d = 0; d < 4; d++)
                    oacc[r][d] = __builtin_amdgcn_mfma_f32_16x16x32_f16(ap[r], bv[d], oacc[r][d], 0, 0, 0);
        }
        // coalesced fp32 attn write from Ps (32KB per tile)
        #pragma unroll
        for (int i = 0; i < 4; i++) {
            int ci = i * 256 + t;
            int row = ci >> 3, c8 = ci & 7;
            f16x8 pv = *(const f16x8*)&Ps[row * 72 + c8 * 8];
            float* dst = attnb + (size_t)(q0 + row) * N_ + m0 + c8 * 8;
            float4 o1, o2;
            o1.x = (float)pv[0]; o1.y = (float)pv[1]; o1.z = (float)pv[2]; o1.w = (float)pv[3];
            o2.x = (float)pv[4]; o2.y = (float)pv[5]; o2.z = (float)pv[6]; o2.w = (float)pv[7];
            *(float4*)dst = o1;
            *((float4*)dst + 1) = o2;
        }
    }
    // write O (f16) to ws, [B*N][C] layout, col = h*64 + d
    #pragma unroll
    for (int r = 0; r < 2; r++)
        #pragma unroll
        for (int d = 0; d < 4; d++) {
            int col = h * D_ + d * 16 + lr;
            #pragma unroll
            for (int g = 0; g < 4; g++) {
                int row = q0 + wv * 32 + r * 16 + lq * 4 + g;
                O[(size_t)(b * N_ + row) * C_ + col] = (_Float16)oacc[r][d][g];
            }
        }
}

// out[m][n] = sum_k O[m][k] * Wp[n][k] + bp[n];  fp32 out
__global__ __launch_bounds__(256) void proj_gemm(const _Float16* __restrict__ ws,
                                                 const float* __restrict__ bp,
                                                 float* __restrict__ out) {
    __shared__ _Float16 As[128 * 72];
    __shared__ _Float16 Bs[128 * 72];
    const _Float16* __restrict__ A = ws + OFF_O;
    const _Float16* __restrict__ W = ws + OFF_W + (size_t)3 * (1u << 20);
    const int t = threadIdx.x;
    const int wv = t >> 6, ln = t & 63, lr = ln & 15, lq = ln >> 4;
    const int wr = (wv >> 1) * 64, wc = (wv & 1) * 64;
    const int m0 = blockIdx.y * 128, n0 = blockIdx.x * 128;
    f32x4 acc[4][4] = {};
    for (int kt = 0; kt < 16; ++kt) {
        const int k0 = kt * 64;
        #pragma unroll
        for (int i = 0; i < 4; i++) {
            int ci = i * 256 + t;
            int row = ci >> 3, c8 = ci & 7;
            f16x8 va = *(const f16x8*)(A + (size_t)(m0 + row) * C_ + k0 + c8 * 8);
            *(f16x8*)&As[row * 72 + c8 * 8] = va;
            f16x8 vb = *(const f16x8*)(W + (size_t)(n0 + row) * C_ + k0 + c8 * 8);
            *(f16x8*)&Bs[row * 72 + c8 * 8] = vb;
        }
        __syncthreads();
        #pragma unroll
        for (int ks = 0; ks < 2; ++ks) {
            f16x8 af[4], bf[4];
            #pragma unroll
            for (int r = 0; r < 4; r++)
                af[r] = *(const f16x8*)&As[(wr + r * 16 + lr) * 72 + ks * 32 + lq * 8];
            #pragma unroll
            for (int c = 0; c < 4; c++)
                bf[c] = *(const f16x8*)&Bs[(wc + c * 16 + lr) * 72 + ks * 32 + lq * 8];
            #pragma unroll
            for (int r = 0; r < 4; r++)
                #pragma unroll
                for (int c = 0; c < 4; c++)
                    acc[r][c] = __builtin_amdgcn_mfma_f32_16x16x32_f16(af[r], bf[c], acc[r][c], 0, 0, 0);
        }
        __syncthreads();
    }
    #pragma unroll
    for (int r = 0; r < 4; r++)
        #pragma unroll
        for (int c = 0; c < 4; c++) {
            int col = n0 + wc + c * 16 + lr;
            float bias = bp[col];
            #pragma unroll
            for (int g = 0; g < 4; ++g) {
                int row = m0 + wr + r * 16 + lq * 4 + g;
                out[(size_t)row * C_ + col] = acc[r][c][g] + bias;
            }
        }
}

extern "C" void kernel_launch(void* const* d_in, const int* in_sizes, int n_in,
                              void* d_out, int out_size, void* d_ws, size_t ws_size,
                              hipStream_t stream) {
    const float* xq = (const float*)d_in[0];
    const float* xk = (const float*)d_in[1];
    const float* xv = (const float*)d_in[2];
    const float* Wq = (const float*)d_in[3];
    const float* Wk = (const float*)d_in[4];
    const float* Wv = (const float*)d_in[5];
    const float* Wp = (const float*)d_in[6];
    const float* bp = (const float*)d_in[7];
    float* out = (float*)d_out;
    _Float16* ws = (_Float16*)d_ws;

    const int n4 = (C_ * C_) / 4;  // 262144 float4 per weight
    const int cb = (n4 + 255) / 256;
    cvt_w<<<cb, 256, 0, stream>>>(Wq, ws + OFF_W + (size_t)0 * (1u << 20), n4);
    cvt_w<<<cb, 256, 0, stream>>>(Wk, ws + OFF_W + (size_t)1 * (1u << 20), n4);
    cvt_w<<<cb, 256, 0, stream>>>(Wv, ws + OFF_W + (size_t)2 * (1u << 20), n4);
    cvt_w<<<cb, 256, 0, stream>>>(Wp, ws + OFF_W + (size_t)3 * (1u << 20), n4);

    qkv_gemm<<<dim3(C_ / 128, M_ / 128, 3), 256, 0, stream>>>(xq, xk, xv, ws);
    attn_kernel<<<dim3(N_ / 128, B_ * H_), 256, 0, stream>>>(ws, out + (size_t)M_ * C_);
    proj_gemm<<<dim3(C_ / 128, M_ / 128, 1), 256, 0, stream>>>(ws, bp, out);
}